// Round 1
// baseline (2046.563 us; speedup 1.0000x reference)
//
#include <hip/hip_runtime.h>
#include <hip/hip_bf16.h>
#include <stdint.h>

// Problem constants
#define H_DIM 4096
#define I_DIM 11008
#define M_TOK 4096   // B*S = 2*2048

typedef __attribute__((ext_vector_type(8))) short short8;  // 8 bf16 (4 VGPRs)
typedef __attribute__((ext_vector_type(4))) float f32x4;   // 4 fp32

static __device__ __forceinline__ float bf2f(unsigned short u) {
    union { uint32_t i; float f; } v; v.i = ((uint32_t)u) << 16; return v.f;
}
static __device__ __forceinline__ unsigned short f2bf(float f) {
    union { float f; uint32_t i; } v; v.f = f;
    uint32_t r = v.i + 0x7FFF + ((v.i >> 16) & 1);   // RNE
    return (unsigned short)(r >> 16);
}

// async global->LDS, 16B per lane; LDS dest must be the wave-uniform base.
static __device__ __forceinline__ void gload16(const void* g, void* l) {
    __builtin_amdgcn_global_load_lds(
        (const __attribute__((address_space(1))) void*)g,
        (__attribute__((address_space(3))) void*)l, 16, 0, 0);
}

// ---------------- small conversion kernels ----------------

// f32 -> bf16, n4 = n/4 float4 groups (n % 4 == 0)
__global__ void k_conv_f32_bf16(const float* __restrict__ in,
                                unsigned short* __restrict__ out, int n4) {
    int stride = gridDim.x * blockDim.x;
    for (int i = blockIdx.x * blockDim.x + threadIdx.x; i < n4; i += stride) {
        f32x4 v = ((const f32x4*)in)[i];
        uint64_t p = (uint64_t)f2bf(v[0]) | ((uint64_t)f2bf(v[1]) << 16) |
                     ((uint64_t)f2bf(v[2]) << 32) | ((uint64_t)f2bf(v[3]) << 48);
        ((uint64_t*)out)[i] = p;
    }
}

// B [32][N] f32 -> BT [N][32] bf16
__global__ void k_transposeB(const float* __restrict__ in,
                             unsigned short* __restrict__ out, int N) {
    int idx = blockIdx.x * blockDim.x + threadIdx.x;
    if (idx < N * 32) {
        int n = idx >> 5, r = idx & 31;
        out[idx] = f2bf(in[r * N + n]);
    }
}

// ---------------- W_eff prep: dequant + rank-32 LR via one MFMA step ----------------
// W[n][k] = (q[n][k]-7.5)*scale[n]*0.005 + 0.02 * sum_r BT[n][r]*Abf[k][r]
__global__ __launch_bounds__(256) void k_wprep(
    const unsigned short* __restrict__ BT,   // [Nw][32] bf16
    const unsigned short* __restrict__ Abf,  // [Kw][32] bf16
    const int* __restrict__ q,               // [Nw][Kw] int32
    const float* __restrict__ scale,         // [Nw]
    unsigned short* __restrict__ W,          // [Nw][Kw] bf16 out
    int Nw, int Kw)
{
    __shared__ unsigned short As[128 * 32];
    __shared__ unsigned short Bs[128 * 32];
    const int tid = threadIdx.x, wid = tid >> 6, lane = tid & 63;
    const int wr = wid >> 1, wc = wid & 1;
    const int brow = blockIdx.y * 128;   // n
    const int bcol = blockIdx.x * 128;   // k
    const int srow = wid * 16 + (lane >> 2), scol = (lane & 3) * 8;

    gload16(BT + (size_t)(brow + srow) * 32 + scol,        &As[wid * 512]);
    gload16(BT + (size_t)(brow + 64 + srow) * 32 + scol,   &As[wid * 512 + 2048]);
    gload16(Abf + (size_t)(bcol + srow) * 32 + scol,       &Bs[wid * 512]);
    gload16(Abf + (size_t)(bcol + 64 + srow) * 32 + scol,  &Bs[wid * 512 + 2048]);
    __syncthreads();

    const int fr = lane & 15, kg = (lane >> 4) * 8;
    f32x4 acc[4][4] = {};
    short8 af[4], bfr[4];
#pragma unroll
    for (int i = 0; i < 4; i++)
        af[i] = *(const short8*)&As[(wr * 64 + i * 16 + fr) * 32 + kg];
#pragma unroll
    for (int j = 0; j < 4; j++)
        bfr[j] = *(const short8*)&Bs[(wc * 64 + j * 16 + fr) * 32 + kg];
#pragma unroll
    for (int i = 0; i < 4; i++)
#pragma unroll
        for (int j = 0; j < 4; j++)
            acc[i][j] = __builtin_amdgcn_mfma_f32_16x16x32_bf16(af[i], bfr[j], acc[i][j], 0, 0, 0);

    const int q4 = lane >> 4;
#pragma unroll
    for (int i = 0; i < 4; i++) {
#pragma unroll
        for (int t = 0; t < 4; t++) {
            int n = brow + wr * 64 + i * 16 + q4 * 4 + t;
            float sc = scale[n] * 0.005f;
#pragma unroll
            for (int j = 0; j < 4; j++) {
                int k = bcol + wc * 64 + j * 16 + fr;
                size_t off = (size_t)n * Kw + k;
                float w = ((float)q[off] - 7.5f) * sc + 0.02f * acc[i][j][t];
                W[off] = f2bf(w);
            }
        }
    }
}

// ---------------- main bf16 GEMM (m97 structure: 128x128, BK=32, gload_lds 16B) ----
// C[M][N] = A[M][K] @ B[N][K]^T ; EPI: 0 store bf16, 1 h=silu(g)*acc bf16, 2 store f32
template <int EPI>
__global__ __launch_bounds__(256) void k_gemm_bt(
    const unsigned short* __restrict__ A,   // [M][K] bf16
    const unsigned short* __restrict__ B,   // [N][K] bf16
    void* __restrict__ C,
    const unsigned short* __restrict__ Gin, // EPI==1: g buffer
    int M, int N, int K)
{
    __shared__ unsigned short As[128 * 32];
    __shared__ unsigned short Bs[128 * 32];
    const int tid = threadIdx.x, wid = tid >> 6, lane = tid & 63;
    const int wr = wid >> 1, wc = wid & 1;
    const int bcol = blockIdx.x * 128;
    const int brow = blockIdx.y * 128;

    const int srow = wid * 16 + (lane >> 2), scol = (lane & 3) * 8;
    const size_t aBase = (size_t)(brow + srow) * K + scol;
    const size_t bBase = (size_t)(bcol + srow) * K + scol;
    unsigned short* aDst = &As[wid * 512];
    unsigned short* bDst = &Bs[wid * 512];

    f32x4 acc[4][4] = {};
    const int fr = lane & 15, kg = (lane >> 4) * 8;

    for (int k0 = 0; k0 < K; k0 += 32) {
        gload16(A + aBase + k0,                   aDst);
        gload16(A + aBase + (size_t)64 * K + k0,  aDst + 2048);
        gload16(B + bBase + k0,                   bDst);
        gload16(B + bBase + (size_t)64 * K + k0,  bDst + 2048);
        __syncthreads();
        short8 af[4], bfr[4];
#pragma unroll
        for (int i = 0; i < 4; i++)
            af[i] = *(const short8*)&As[(wr * 64 + i * 16 + fr) * 32 + kg];
#pragma unroll
        for (int j = 0; j < 4; j++)
            bfr[j] = *(const short8*)&Bs[(wc * 64 + j * 16 + fr) * 32 + kg];
#pragma unroll
        for (int i = 0; i < 4; i++)
#pragma unroll
            for (int j = 0; j < 4; j++)
                acc[i][j] = __builtin_amdgcn_mfma_f32_16x16x32_bf16(af[i], bfr[j], acc[i][j], 0, 0, 0);
        __syncthreads();
    }

    const int q4 = lane >> 4;
#pragma unroll
    for (int i = 0; i < 4; i++) {
#pragma unroll
        for (int j = 0; j < 4; j++) {
#pragma unroll
            for (int t = 0; t < 4; t++) {
                int m = brow + wr * 64 + i * 16 + q4 * 4 + t;
                int n = bcol + wc * 64 + j * 16 + fr;
                size_t off = (size_t)m * N + n;
                float v = acc[i][j][t];
                if (EPI == 0) {
                    ((unsigned short*)C)[off] = f2bf(v);
                } else if (EPI == 1) {
                    float g = bf2f(Gin[off]);
                    float s = g / (1.0f + __expf(-g));   // silu(g)
                    ((unsigned short*)C)[off] = f2bf(s * v);
                } else {
                    ((float*)C)[off] = v;
                }
            }
        }
    }
}

// ---------------- host launch ----------------
extern "C" void kernel_launch(void* const* d_in, const int* in_sizes, int n_in,
                              void* d_out, int out_size, void* d_ws, size_t ws_size,
                              hipStream_t stream) {
    (void)in_sizes; (void)n_in; (void)out_size; (void)ws_size;
    const float* x          = (const float*)d_in[0];
    const int*   gate_q     = (const int*)d_in[1];
    const float* gate_scale = (const float*)d_in[2];
    const float* gate_A     = (const float*)d_in[3];
    const float* gate_B     = (const float*)d_in[4];
    const int*   up_q       = (const int*)d_in[5];
    const float* up_scale   = (const float*)d_in[6];
    const float* up_A       = (const float*)d_in[7];
    const float* up_B       = (const float*)d_in[8];
    const int*   down_q     = (const int*)d_in[9];
    const float* down_scale = (const float*)d_in[10];
    const float* down_A     = (const float*)d_in[11];
    const float* down_B     = (const float*)d_in[12];

    char* ws = (char*)d_ws;
    size_t off = 0;
    auto alloc = [&](size_t bytes) {
        void* p = ws + off; off += (bytes + 255) & ~(size_t)255; return p;
    };
    unsigned short* xbf  = (unsigned short*)alloc((size_t)M_TOK * H_DIM * 2);
    unsigned short* wg   = (unsigned short*)alloc((size_t)I_DIM * H_DIM * 2);
    unsigned short* wu   = (unsigned short*)alloc((size_t)I_DIM * H_DIM * 2);
    unsigned short* wd   = (unsigned short*)alloc((size_t)H_DIM * I_DIM * 2);
    unsigned short* gbuf = (unsigned short*)alloc((size_t)M_TOK * I_DIM * 2);
    unsigned short* AgBf = (unsigned short*)alloc((size_t)H_DIM * 32 * 2);
    unsigned short* AuBf = (unsigned short*)alloc((size_t)H_DIM * 32 * 2);
    unsigned short* AdBf = (unsigned short*)alloc((size_t)I_DIM * 32 * 2);
    unsigned short* BgT  = (unsigned short*)alloc((size_t)I_DIM * 32 * 2);
    unsigned short* BuT  = (unsigned short*)alloc((size_t)I_DIM * 32 * 2);
    unsigned short* BdT  = (unsigned short*)alloc((size_t)H_DIM * 32 * 2);

    // small conversions
    k_conv_f32_bf16<<<128, 256, 0, stream>>>(gate_A, AgBf, (H_DIM * 32) / 4);
    k_conv_f32_bf16<<<128, 256, 0, stream>>>(up_A,   AuBf, (H_DIM * 32) / 4);
    k_conv_f32_bf16<<<344, 256, 0, stream>>>(down_A, AdBf, (I_DIM * 32) / 4);
    k_transposeB<<<(I_DIM * 32 + 255) / 256, 256, 0, stream>>>(gate_B, BgT, I_DIM);
    k_transposeB<<<(I_DIM * 32 + 255) / 256, 256, 0, stream>>>(up_B,   BuT, I_DIM);
    k_transposeB<<<(H_DIM * 32 + 255) / 256, 256, 0, stream>>>(down_B, BdT, H_DIM);
    // x -> bf16
    k_conv_f32_bf16<<<2048, 256, 0, stream>>>(x, xbf, (M_TOK * H_DIM) / 4);

    // W_eff = dequant + 0.02*(A@B)^T   (bf16)
    k_wprep<<<dim3(H_DIM / 128, I_DIM / 128), 256, 0, stream>>>(BgT, AgBf, gate_q, gate_scale, wg, I_DIM, H_DIM);
    k_wprep<<<dim3(H_DIM / 128, I_DIM / 128), 256, 0, stream>>>(BuT, AuBf, up_q,   up_scale,   wu, I_DIM, H_DIM);
    k_wprep<<<dim3(I_DIM / 128, H_DIM / 128), 256, 0, stream>>>(BdT, AdBf, down_q, down_scale, wd, H_DIM, I_DIM);

    // g = x @ Wg^T          (bf16 out)
    k_gemm_bt<0><<<dim3(I_DIM / 128, M_TOK / 128), 256, 0, stream>>>(xbf, wg, gbuf, nullptr, M_TOK, I_DIM, H_DIM);
    // h = silu(g) * (x @ Wu^T)   (in-place over g)
    k_gemm_bt<1><<<dim3(I_DIM / 128, M_TOK / 128), 256, 0, stream>>>(xbf, wu, gbuf, gbuf, M_TOK, I_DIM, H_DIM);
    // out = h @ Wd^T        (f32)
    k_gemm_bt<2><<<dim3(H_DIM / 128, M_TOK / 128), 256, 0, stream>>>(gbuf, wd, d_out, nullptr, M_TOK, H_DIM, I_DIM);
}

// Round 2
// 1324.764 us; speedup vs baseline: 1.5449x; 1.5449x over previous
//
#include <hip/hip_runtime.h>
#include <hip/hip_bf16.h>
#include <stdint.h>

// Problem constants
#define H_DIM 4096
#define I_DIM 11008
#define M_TOK 4096   // B*S = 2*2048

typedef __attribute__((ext_vector_type(8))) short short8;  // 8 bf16 (4 VGPRs)
typedef __attribute__((ext_vector_type(4))) float f32x4;   // 4 fp32

static __device__ __forceinline__ float bf2f(unsigned short u) {
    union { uint32_t i; float f; } v; v.i = ((uint32_t)u) << 16; return v.f;
}
static __device__ __forceinline__ unsigned short f2bf(float f) {
    union { float f; uint32_t i; } v; v.f = f;
    uint32_t r = v.i + 0x7FFF + ((v.i >> 16) & 1);   // RNE
    return (unsigned short)(r >> 16);
}

// async global->LDS, 16B per lane; LDS dest is the wave-uniform base.
static __device__ __forceinline__ void gload16(const void* g, void* l) {
    __builtin_amdgcn_global_load_lds(
        (const __attribute__((address_space(1))) void*)g,
        (__attribute__((address_space(3))) void*)l, 16, 0, 0);
}

// ---------------- small conversion kernels ----------------

__global__ void k_conv_f32_bf16(const float* __restrict__ in,
                                unsigned short* __restrict__ out, int n4) {
    int stride = gridDim.x * blockDim.x;
    for (int i = blockIdx.x * blockDim.x + threadIdx.x; i < n4; i += stride) {
        f32x4 v = ((const f32x4*)in)[i];
        uint64_t p = (uint64_t)f2bf(v[0]) | ((uint64_t)f2bf(v[1]) << 16) |
                     ((uint64_t)f2bf(v[2]) << 32) | ((uint64_t)f2bf(v[3]) << 48);
        ((uint64_t*)out)[i] = p;
    }
}

// B [32][N] f32 -> BT [N][32] bf16
__global__ void k_transposeB(const float* __restrict__ in,
                             unsigned short* __restrict__ out, int N) {
    int idx = blockIdx.x * blockDim.x + threadIdx.x;
    if (idx < N * 32) {
        int n = idx >> 5, r = idx & 31;
        out[idx] = f2bf(in[r * N + n]);
    }
}

// ---------------- W_eff prep: dequant + rank-32 LR via one MFMA step ----------------
__global__ __launch_bounds__(256) void k_wprep(
    const unsigned short* __restrict__ BT,   // [Nw][32] bf16
    const unsigned short* __restrict__ Abf,  // [Kw][32] bf16
    const int* __restrict__ q,               // [Nw][Kw] int32
    const float* __restrict__ scale,         // [Nw]
    unsigned short* __restrict__ W,          // [Nw][Kw] bf16 out
    int Nw, int Kw)
{
    __shared__ unsigned short As[128 * 32];
    __shared__ unsigned short Bs[128 * 32];
    const int tid = threadIdx.x, wid = tid >> 6, lane = tid & 63;
    const int wr = wid >> 1, wc = wid & 1;
    const int brow = blockIdx.y * 128;   // n
    const int bcol = blockIdx.x * 128;   // k
    const int srow = wid * 16 + (lane >> 2), scol = (lane & 3) * 8;

    gload16(BT + (size_t)(brow + srow) * 32 + scol,        &As[wid * 512]);
    gload16(BT + (size_t)(brow + 64 + srow) * 32 + scol,   &As[wid * 512 + 2048]);
    gload16(Abf + (size_t)(bcol + srow) * 32 + scol,       &Bs[wid * 512]);
    gload16(Abf + (size_t)(bcol + 64 + srow) * 32 + scol,  &Bs[wid * 512 + 2048]);
    __syncthreads();

    const int fr = lane & 15, kg = (lane >> 4) * 8;
    f32x4 acc[4][4] = {};
    short8 af[4], bfr[4];
#pragma unroll
    for (int i = 0; i < 4; i++)
        af[i] = *(const short8*)&As[(wr * 64 + i * 16 + fr) * 32 + kg];
#pragma unroll
    for (int j = 0; j < 4; j++)
        bfr[j] = *(const short8*)&Bs[(wc * 64 + j * 16 + fr) * 32 + kg];
#pragma unroll
    for (int i = 0; i < 4; i++)
#pragma unroll
        for (int j = 0; j < 4; j++)
            acc[i][j] = __builtin_amdgcn_mfma_f32_16x16x32_bf16(af[i], bfr[j], acc[i][j], 0, 0, 0);

    const int q4 = lane >> 4;
#pragma unroll
    for (int i = 0; i < 4; i++) {
#pragma unroll
        for (int t = 0; t < 4; t++) {
            int n = brow + wr * 64 + i * 16 + q4 * 4 + t;
            float sc = scale[n] * 0.005f;
#pragma unroll
            for (int j = 0; j < 4; j++) {
                int k = bcol + wc * 64 + j * 16 + fr;
                size_t off = (size_t)n * Kw + k;
                float w = ((float)q[off] - 7.5f) * sc + 0.02f * acc[i][j][t];
                W[off] = f2bf(w);
            }
        }
    }
}

// ---------------- main bf16 GEMM: 256x256 tile, BK=64, counted vmcnt, T2 swizzle ----
// C[M][N] = A[M][K] @ B[N][K]^T
// EPI: 0 store bf16, 1 h=silu(g)*acc bf16, 2 store f32
// 512 threads = 8 waves (2 M x 4 N); per-wave output 128x64.
// LDS: 2 buffers x (A 256x64 + B 256x64) bf16 = 128 KiB (dynamic).
// Swizzle: 16B slot s within 128B row holds global slot s ^ (row&7);
//   applied on the global SOURCE of global_load_lds (linear LDS dest) and
//   on the ds_read address (both-sides, rule 21). Uniform 8 lanes/slot.
template <int EPI>
__global__ __launch_bounds__(512, 1) void k_gemm256(
    const unsigned short* __restrict__ A,   // [M][K] bf16
    const unsigned short* __restrict__ B,   // [N][K] bf16
    void* __restrict__ C,
    const unsigned short* __restrict__ Gin, // EPI==1: g buffer
    int M, int N, int K)
{
    extern __shared__ unsigned short smem[];   // 65536 elems = 128 KiB
    const int tid = threadIdx.x, wid = tid >> 6, lane = tid & 63;
    const int wr = wid >> 2, wc = wid & 3;

    // T1: bijective XCD swizzle on flattened block id (nwg % 8 == 0 here)
    const int gx = N >> 8;
    const int nwg = gx * (M >> 8);
    int orig = blockIdx.y * gx + blockIdx.x;
    int q8 = nwg >> 3, r8 = nwg & 7;
    int xcd = orig & 7, lid = orig >> 3;
    int wg = (xcd < r8 ? xcd * (q8 + 1) : r8 * (q8 + 1) + (xcd - r8) * q8) + lid;
    const int bcol = (wg % gx) << 8;
    const int brow = (wg / gx) << 8;

    // staging addresses: call c covers rows [c*64 + wid*8, +8); lane l ->
    // row l>>3, LDS slot l&7, global source slot (l&7)^(l>>3)
    const int rg = lane >> 3;
    const int ss = ((lane & 7) ^ rg) * 8;    // source col offset (bf16 elems)
    const unsigned short* aS[4];
    const unsigned short* bS[4];
#pragma unroll
    for (int c = 0; c < 4; c++) {
        int row = c * 64 + wid * 8 + rg;
        aS[c] = A + (size_t)(brow + row) * K + ss;
        bS[c] = B + (size_t)(bcol + row) * K + ss;
    }

    f32x4 acc[8][4] = {};
    const int fr = lane & 15, qk = lane >> 4, f7 = fr & 7;
    const int NT = K >> 6;
    int cur = 0;

    auto STAGE = [&](int k0, int b) {
        unsigned short* base = smem + b * 32768;
#pragma unroll
        for (int c = 0; c < 4; c++)
            gload16(aS[c] + k0, base + (c * 64 + wid * 8) * 64);
#pragma unroll
        for (int c = 0; c < 4; c++)
            gload16(bS[c] + k0, base + 16384 + (c * 64 + wid * 8) * 64);
    };

    STAGE(0, 0);                               // 8 loads in flight
    for (int t = 0; t < NT; ++t) {
        if (t + 1 < NT) {
            STAGE((t + 1) << 6, cur ^ 1);      // +8 loads (stay in flight)
            asm volatile("s_waitcnt vmcnt(8)" ::: "memory");  // tile t landed
        } else {
            asm volatile("s_waitcnt vmcnt(0)" ::: "memory");
        }
        __builtin_amdgcn_s_barrier();          // buf[cur] visible to all waves

        const unsigned short* Ab = smem + cur * 32768;
        const unsigned short* Bb = Ab + 16384;
#pragma unroll
        for (int kk = 0; kk < 2; ++kk) {
            const int sw = (((kk << 2) | qk) ^ f7) << 3;  // swizzled col (elems)
            short8 af[8], bf[4];
#pragma unroll
            for (int i = 0; i < 8; ++i)
                af[i] = *(const short8*)&Ab[(wr * 128 + i * 16 + fr) * 64 + sw];
#pragma unroll
            for (int j = 0; j < 4; ++j)
                bf[j] = *(const short8*)&Bb[(wc * 64 + j * 16 + fr) * 64 + sw];
            __builtin_amdgcn_s_setprio(1);
#pragma unroll
            for (int i = 0; i < 8; ++i)
#pragma unroll
                for (int j = 0; j < 4; ++j)
                    acc[i][j] = __builtin_amdgcn_mfma_f32_16x16x32_bf16(af[i], bf[j], acc[i][j], 0, 0, 0);
            __builtin_amdgcn_s_setprio(0);
        }
        __builtin_amdgcn_s_barrier();          // all reads of buf[cur] done
        cur ^= 1;
    }

    // epilogue
    const int q4 = lane >> 4;
#pragma unroll
    for (int i = 0; i < 8; ++i) {
#pragma unroll
        for (int j = 0; j < 4; ++j) {
#pragma unroll
            for (int tt = 0; tt < 4; ++tt) {
                int m = brow + wr * 128 + i * 16 + q4 * 4 + tt;
                int n = bcol + wc * 64 + j * 16 + fr;
                size_t off = (size_t)m * N + n;
                float v = acc[i][j][tt];
                if (EPI == 0) {
                    ((unsigned short*)C)[off] = f2bf(v);
                } else if (EPI == 1) {
                    float g = bf2f(Gin[off]);
                    float s = g / (1.0f + __expf(-g));   // silu(g)
                    ((unsigned short*)C)[off] = f2bf(s * v);
                } else {
                    ((float*)C)[off] = v;
                }
            }
        }
    }
}

// ---------------- host launch ----------------
extern "C" void kernel_launch(void* const* d_in, const int* in_sizes, int n_in,
                              void* d_out, int out_size, void* d_ws, size_t ws_size,
                              hipStream_t stream) {
    (void)in_sizes; (void)n_in; (void)out_size; (void)ws_size;
    const float* x          = (const float*)d_in[0];
    const int*   gate_q     = (const int*)d_in[1];
    const float* gate_scale = (const float*)d_in[2];
    const float* gate_A     = (const float*)d_in[3];
    const float* gate_B     = (const float*)d_in[4];
    const int*   up_q       = (const int*)d_in[5];
    const float* up_scale   = (const float*)d_in[6];
    const float* up_A       = (const float*)d_in[7];
    const float* up_B       = (const float*)d_in[8];
    const int*   down_q     = (const int*)d_in[9];
    const float* down_scale = (const float*)d_in[10];
    const float* down_A     = (const float*)d_in[11];
    const float* down_B     = (const float*)d_in[12];

    char* ws = (char*)d_ws;
    size_t off = 0;
    auto alloc = [&](size_t bytes) {
        void* p = ws + off; off += (bytes + 255) & ~(size_t)255; return p;
    };
    unsigned short* xbf  = (unsigned short*)alloc((size_t)M_TOK * H_DIM * 2);
    unsigned short* wg   = (unsigned short*)alloc((size_t)I_DIM * H_DIM * 2);
    unsigned short* wu   = (unsigned short*)alloc((size_t)I_DIM * H_DIM * 2);
    unsigned short* wd   = (unsigned short*)alloc((size_t)H_DIM * I_DIM * 2);
    unsigned short* gbuf = (unsigned short*)alloc((size_t)M_TOK * I_DIM * 2);
    unsigned short* AgBf = (unsigned short*)alloc((size_t)H_DIM * 32 * 2);
    unsigned short* AuBf = (unsigned short*)alloc((size_t)H_DIM * 32 * 2);
    unsigned short* AdBf = (unsigned short*)alloc((size_t)I_DIM * 32 * 2);
    unsigned short* BgT  = (unsigned short*)alloc((size_t)I_DIM * 32 * 2);
    unsigned short* BuT  = (unsigned short*)alloc((size_t)I_DIM * 32 * 2);
    unsigned short* BdT  = (unsigned short*)alloc((size_t)H_DIM * 32 * 2);

    // enable 128 KiB dynamic LDS for the GEMM instantiations (idempotent)
    (void)hipFuncSetAttribute((const void*)k_gemm256<0>,
        hipFuncAttributeMaxDynamicSharedMemorySize, 131072);
    (void)hipFuncSetAttribute((const void*)k_gemm256<1>,
        hipFuncAttributeMaxDynamicSharedMemorySize, 131072);
    (void)hipFuncSetAttribute((const void*)k_gemm256<2>,
        hipFuncAttributeMaxDynamicSharedMemorySize, 131072);

    // small conversions
    k_conv_f32_bf16<<<128, 256, 0, stream>>>(gate_A, AgBf, (H_DIM * 32) / 4);
    k_conv_f32_bf16<<<128, 256, 0, stream>>>(up_A,   AuBf, (H_DIM * 32) / 4);
    k_conv_f32_bf16<<<344, 256, 0, stream>>>(down_A, AdBf, (I_DIM * 32) / 4);
    k_transposeB<<<(I_DIM * 32 + 255) / 256, 256, 0, stream>>>(gate_B, BgT, I_DIM);
    k_transposeB<<<(I_DIM * 32 + 255) / 256, 256, 0, stream>>>(up_B,   BuT, I_DIM);
    k_transposeB<<<(H_DIM * 32 + 255) / 256, 256, 0, stream>>>(down_B, BdT, H_DIM);
    k_conv_f32_bf16<<<2048, 256, 0, stream>>>(x, xbf, (M_TOK * H_DIM) / 4);

    // W_eff = dequant + 0.02*(A@B)^T   (bf16)
    k_wprep<<<dim3(H_DIM / 128, I_DIM / 128), 256, 0, stream>>>(BgT, AgBf, gate_q, gate_scale, wg, I_DIM, H_DIM);
    k_wprep<<<dim3(H_DIM / 128, I_DIM / 128), 256, 0, stream>>>(BuT, AuBf, up_q,   up_scale,   wu, I_DIM, H_DIM);
    k_wprep<<<dim3(I_DIM / 128, H_DIM / 128), 256, 0, stream>>>(BdT, AdBf, down_q, down_scale, wd, H_DIM, I_DIM);

    // g = x @ Wg^T          (bf16 out)
    k_gemm256<0><<<dim3(I_DIM / 256, M_TOK / 256), 512, 131072, stream>>>(xbf, wg, gbuf, nullptr, M_TOK, I_DIM, H_DIM);
    // h = silu(g) * (x @ Wu^T)   (in-place over g)
    k_gemm256<1><<<dim3(I_DIM / 256, M_TOK / 256), 512, 131072, stream>>>(xbf, wu, gbuf, gbuf, M_TOK, I_DIM, H_DIM);
    // out = h @ Wd^T        (f32)
    k_gemm256<2><<<dim3(H_DIM / 256, M_TOK / 256), 512, 131072, stream>>>(gbuf, wd, d_out, nullptr, M_TOK, H_DIM, I_DIM);
}

// Round 3
// 1238.864 us; speedup vs baseline: 1.6520x; 1.0693x over previous
//
#include <hip/hip_runtime.h>
#include <hip/hip_bf16.h>
#include <stdint.h>

// Problem constants
#define H_DIM 4096
#define I_DIM 11008
#define M_TOK 4096   // B*S = 2*2048

typedef __attribute__((ext_vector_type(8))) short short8;  // 8 bf16 (4 VGPRs)
typedef __attribute__((ext_vector_type(4))) float f32x4;   // 4 fp32

static __device__ __forceinline__ float bf2f(unsigned short u) {
    union { uint32_t i; float f; } v; v.i = ((uint32_t)u) << 16; return v.f;
}
static __device__ __forceinline__ unsigned short f2bf(float f) {
    union { float f; uint32_t i; } v; v.f = f;
    uint32_t r = v.i + 0x7FFF + ((v.i >> 16) & 1);   // RNE
    return (unsigned short)(r >> 16);
}

// async global->LDS, 16B per lane; LDS dest is the wave-uniform base.
static __device__ __forceinline__ void gload16(const void* g, void* l) {
    __builtin_amdgcn_global_load_lds(
        (const __attribute__((address_space(1))) void*)g,
        (__attribute__((address_space(3))) void*)l, 16, 0, 0);
}

// ---------------- small conversion kernels ----------------

__global__ void k_conv_f32_bf16(const float* __restrict__ in,
                                unsigned short* __restrict__ out, int n4) {
    int stride = gridDim.x * blockDim.x;
    for (int i = blockIdx.x * blockDim.x + threadIdx.x; i < n4; i += stride) {
        f32x4 v = ((const f32x4*)in)[i];
        uint64_t p = (uint64_t)f2bf(v[0]) | ((uint64_t)f2bf(v[1]) << 16) |
                     ((uint64_t)f2bf(v[2]) << 32) | ((uint64_t)f2bf(v[3]) << 48);
        ((uint64_t*)out)[i] = p;
    }
}

// B [32][N] f32 -> BT [N][32] bf16
__global__ void k_transposeB(const float* __restrict__ in,
                             unsigned short* __restrict__ out, int N) {
    int idx = blockIdx.x * blockDim.x + threadIdx.x;
    if (idx < N * 32) {
        int n = idx >> 5, r = idx & 31;
        out[idx] = f2bf(in[r * N + n]);
    }
}

// ---------------- W_eff prep: dequant + rank-32 LR via one MFMA step ----------------
__global__ __launch_bounds__(256) void k_wprep(
    const unsigned short* __restrict__ BT,   // [Nw][32] bf16
    const unsigned short* __restrict__ Abf,  // [Kw][32] bf16
    const int* __restrict__ q,               // [Nw][Kw] int32
    const float* __restrict__ scale,         // [Nw]
    unsigned short* __restrict__ W,          // [Nw][Kw] bf16 out
    int Nw, int Kw)
{
    __shared__ unsigned short As[128 * 32];
    __shared__ unsigned short Bs[128 * 32];
    const int tid = threadIdx.x, wid = tid >> 6, lane = tid & 63;
    const int wr = wid >> 1, wc = wid & 1;
    const int brow = blockIdx.y * 128;   // n
    const int bcol = blockIdx.x * 128;   // k
    const int srow = wid * 16 + (lane >> 2), scol = (lane & 3) * 8;

    gload16(BT + (size_t)(brow + srow) * 32 + scol,        &As[wid * 512]);
    gload16(BT + (size_t)(brow + 64 + srow) * 32 + scol,   &As[wid * 512 + 2048]);
    gload16(Abf + (size_t)(bcol + srow) * 32 + scol,       &Bs[wid * 512]);
    gload16(Abf + (size_t)(bcol + 64 + srow) * 32 + scol,  &Bs[wid * 512 + 2048]);
    __syncthreads();

    const int fr = lane & 15, kg = (lane >> 4) * 8;
    f32x4 acc[4][4] = {};
    short8 af[4], bfr[4];
#pragma unroll
    for (int i = 0; i < 4; i++)
        af[i] = *(const short8*)&As[(wr * 64 + i * 16 + fr) * 32 + kg];
#pragma unroll
    for (int j = 0; j < 4; j++)
        bfr[j] = *(const short8*)&Bs[(wc * 64 + j * 16 + fr) * 32 + kg];
#pragma unroll
    for (int i = 0; i < 4; i++)
#pragma unroll
        for (int j = 0; j < 4; j++)
            acc[i][j] = __builtin_amdgcn_mfma_f32_16x16x32_bf16(af[i], bfr[j], acc[i][j], 0, 0, 0);

    const int q4 = lane >> 4;
#pragma unroll
    for (int i = 0; i < 4; i++) {
#pragma unroll
        for (int t = 0; t < 4; t++) {
            int n = brow + wr * 64 + i * 16 + q4 * 4 + t;
            float sc = scale[n] * 0.005f;
#pragma unroll
            for (int j = 0; j < 4; j++) {
                int k = bcol + wc * 64 + j * 16 + fr;
                size_t off = (size_t)n * Kw + k;
                float w = ((float)q[off] - 7.5f) * sc + 0.02f * acc[i][j][t];
                W[off] = f2bf(w);
            }
        }
    }
}

// ---------------- main bf16 GEMM: 256x256, BK=64, 4-phase/K-tile pipeline ----------
// C[M][N] = A[M][K] @ B[N][K]^T ; EPI: 0 bf16, 1 h=silu(g)*acc bf16, 2 f32
// 512 threads = 8 waves. Per-wave C: 128 rows x 64 cols, as
//   A-frag i: row = (i>>2)*128 + wr*64 + (i&3)*16   (ih = i>>2 selects A-half)
//   B-frag j: row = (j>>1)*128 + wc*32 + (j&1)*16   (jh = j>>1 selects B-half)
// so MFMA quadrant (ih,jh) touches ONLY A-half ih + B-half jh.
// Phases per K-tile: P0=(0,0) reads A0+B0; P1=(0,1) reads B1; P2=(1,0) reads A1;
// P3=(1,1) all-reg. Stage order (1 half-tile = 2 gloads per phase): A0,B0,B1,A1
// of tile t+1 -> need-order of the next tile. vmcnt(6) = 3 half-tiles in flight
// certifies exactly the half-tile consumed this phase (verified by stage index:
// at t:Pq after staging s(4t+4+q), vmcnt(6) lands through s(4t+q+1)).
template <int EPI>
__global__ __launch_bounds__(512, 1) void k_gemm256(
    const unsigned short* __restrict__ A,   // [M][K] bf16
    const unsigned short* __restrict__ B,   // [N][K] bf16
    void* __restrict__ C,
    const unsigned short* __restrict__ Gin, // EPI==1: g buffer
    int M, int N, int K)
{
    extern __shared__ unsigned short smem[];   // 65536 elems = 128 KiB
    const int tid = threadIdx.x, wid = tid >> 6, lane = tid & 63;
    const int wr = wid >> 2, wc = wid & 3;

    // T1: bijective XCD swizzle
    const int gx = N >> 8;
    const int nwg = gx * (M >> 8);
    int orig = blockIdx.y * gx + blockIdx.x;
    int q8 = nwg >> 3, r8 = nwg & 7;
    int xcd = orig & 7, lid = orig >> 3;
    int wg = (xcd < r8 ? xcd * (q8 + 1) : r8 * (q8 + 1) + (xcd - r8) * q8) + lid;
    const int bcol = (wg % gx) << 8;
    const int brow = (wg / gx) << 8;

    // staging: quarter c covers rows [c*64 + wid*8, +8); lane l -> row l>>3,
    // LDS slot l&7, pre-swizzled global source slot (l&7)^(l>>3)
    const int rg = lane >> 3;
    const int ss = ((lane & 7) ^ rg) * 8;
    const unsigned short* aS[4];
    const unsigned short* bS[4];
#pragma unroll
    for (int c = 0; c < 4; c++) {
        int row = c * 64 + wid * 8 + rg;
        aS[c] = A + (size_t)(brow + row) * K + ss;
        bS[c] = B + (size_t)(bcol + row) * K + ss;
    }
    const int ldw = wid * 512;   // wave chunk within a 64-row quarter (elems)

    f32x4 acc[8][4] = {};
    short8 af[4][2];       // A-frags for current ih (i4 x kk)
    short8 bf[2][2][2];    // B-frags, both jh kept whole K-tile (jh x j2 x kk)
    const int fr = lane & 15, qk = lane >> 4, f7 = fr & 7;
    const int NT = K >> 6;

#define STG(p, k0, doff) gload16((p) + (k0), smem + (doff) + ldw)

    auto DS_A = [&](const unsigned short* Ab, int ih) {
#pragma unroll
        for (int i4 = 0; i4 < 4; ++i4)
#pragma unroll
            for (int kk = 0; kk < 2; ++kk)
                af[i4][kk] = *(const short8*)&Ab[
                    (ih * 128 + wr * 64 + i4 * 16 + fr) * 64 +
                    ((((kk << 2) | qk) ^ f7) << 3)];
    };
    auto DS_B = [&](const unsigned short* Bb, int jh) {
#pragma unroll
        for (int j2 = 0; j2 < 2; ++j2)
#pragma unroll
            for (int kk = 0; kk < 2; ++kk)
                bf[jh][j2][kk] = *(const short8*)&Bb[
                    (jh * 128 + wc * 32 + j2 * 16 + fr) * 64 +
                    ((((kk << 2) | qk) ^ f7) << 3)];
    };
    auto MFMAQ = [&](int ih, int jh) {
        __builtin_amdgcn_s_setprio(1);
#pragma unroll
        for (int i4 = 0; i4 < 4; ++i4)
#pragma unroll
            for (int j2 = 0; j2 < 2; ++j2)
#pragma unroll
                for (int kk = 0; kk < 2; ++kk)
                    acc[ih * 4 + i4][jh * 2 + j2] =
                        __builtin_amdgcn_mfma_f32_16x16x32_bf16(
                            af[i4][kk], bf[jh][j2][kk],
                            acc[ih * 4 + i4][jh * 2 + j2], 0, 0, 0);
        __builtin_amdgcn_s_setprio(0);
    };

    // prologue: stage tile 0 in need-order A0,B0,B1,A1 (8 gloads)
    STG(aS[0], 0, 0);            STG(aS[1], 0, 4096);
    STG(bS[0], 0, 16384);        STG(bS[1], 0, 16384 + 4096);
    STG(bS[2], 0, 16384 + 8192); STG(bS[3], 0, 16384 + 12288);
    STG(aS[2], 0, 8192);         STG(aS[3], 0, 12288);

    for (int t = 0; t < NT - 1; ++t) {
        const int bsel = (t & 1) * 32768, nsel = 32768 - bsel;
        const unsigned short* Ab = smem + bsel;
        const unsigned short* Bb = Ab + 16384;
        const int k1 = (t + 1) << 6;
        // P0: quadrant (0,0); stage A0(t+1)
        STG(aS[0], k1, nsel);            STG(aS[1], k1, nsel + 4096);
        asm volatile("s_waitcnt vmcnt(6)" ::: "memory");
        __builtin_amdgcn_s_barrier();
        DS_A(Ab, 0); DS_B(Bb, 0);
        MFMAQ(0, 0);
        __builtin_amdgcn_s_barrier();
        // P1: quadrant (0,1); stage B0(t+1)
        STG(bS[0], k1, nsel + 16384);    STG(bS[1], k1, nsel + 16384 + 4096);
        asm volatile("s_waitcnt vmcnt(6)" ::: "memory");
        __builtin_amdgcn_s_barrier();
        DS_B(Bb, 1);
        MFMAQ(0, 1);
        __builtin_amdgcn_s_barrier();
        // P2: quadrant (1,0); stage B1(t+1)
        STG(bS[2], k1, nsel + 16384 + 8192); STG(bS[3], k1, nsel + 16384 + 12288);
        asm volatile("s_waitcnt vmcnt(6)" ::: "memory");
        __builtin_amdgcn_s_barrier();
        DS_A(Ab, 1);
        MFMAQ(1, 0);
        __builtin_amdgcn_s_barrier();
        // P3: quadrant (1,1) all-reg; stage A1(t+1)
        STG(aS[2], k1, nsel + 8192);     STG(aS[3], k1, nsel + 12288);
        __builtin_amdgcn_s_barrier();
        MFMAQ(1, 1);
        __builtin_amdgcn_s_barrier();
    }

    // final tile t = NT-1 (no staging; drain counts 4/2/0)
    {
        const unsigned short* Ab = smem + ((NT - 1) & 1) * 32768;
        const unsigned short* Bb = Ab + 16384;
        asm volatile("s_waitcnt vmcnt(4)" ::: "memory");
        __builtin_amdgcn_s_barrier();
        DS_A(Ab, 0); DS_B(Bb, 0);
        MFMAQ(0, 0);
        asm volatile("s_waitcnt vmcnt(2)" ::: "memory");
        __builtin_amdgcn_s_barrier();
        DS_B(Bb, 1);
        MFMAQ(0, 1);
        asm volatile("s_waitcnt vmcnt(0)" ::: "memory");
        __builtin_amdgcn_s_barrier();
        DS_A(Ab, 1);
        MFMAQ(1, 0);
        MFMAQ(1, 1);
    }
#undef STG

    // epilogue
    const int q4 = lane >> 4;
#pragma unroll
    for (int i = 0; i < 8; ++i) {
#pragma unroll
        for (int j = 0; j < 4; ++j) {
#pragma unroll
            for (int tt = 0; tt < 4; ++tt) {
                int m = brow + (i >> 2) * 128 + wr * 64 + (i & 3) * 16 + q4 * 4 + tt;
                int n = bcol + (j >> 1) * 128 + wc * 32 + (j & 1) * 16 + fr;
                size_t off = (size_t)m * N + n;
                float v = acc[i][j][tt];
                if (EPI == 0) {
                    ((unsigned short*)C)[off] = f2bf(v);
                } else if (EPI == 1) {
                    float g = bf2f(Gin[off]);
                    float s = g / (1.0f + __expf(-g));   // silu(g)
                    ((unsigned short*)C)[off] = f2bf(s * v);
                } else {
                    ((float*)C)[off] = v;
                }
            }
        }
    }
}

// ---------------- host launch ----------------
extern "C" void kernel_launch(void* const* d_in, const int* in_sizes, int n_in,
                              void* d_out, int out_size, void* d_ws, size_t ws_size,
                              hipStream_t stream) {
    (void)in_sizes; (void)n_in; (void)out_size; (void)ws_size;
    const float* x          = (const float*)d_in[0];
    const int*   gate_q     = (const int*)d_in[1];
    const float* gate_scale = (const float*)d_in[2];
    const float* gate_A     = (const float*)d_in[3];
    const float* gate_B     = (const float*)d_in[4];
    const int*   up_q       = (const int*)d_in[5];
    const float* up_scale   = (const float*)d_in[6];
    const float* up_A       = (const float*)d_in[7];
    const float* up_B       = (const float*)d_in[8];
    const int*   down_q     = (const int*)d_in[9];
    const float* down_scale = (const float*)d_in[10];
    const float* down_A     = (const float*)d_in[11];
    const float* down_B     = (const float*)d_in[12];

    char* ws = (char*)d_ws;
    size_t off = 0;
    auto alloc = [&](size_t bytes) {
        void* p = ws + off; off += (bytes + 255) & ~(size_t)255; return p;
    };
    unsigned short* xbf  = (unsigned short*)alloc((size_t)M_TOK * H_DIM * 2);
    unsigned short* wg   = (unsigned short*)alloc((size_t)I_DIM * H_DIM * 2);
    unsigned short* wu   = (unsigned short*)alloc((size_t)I_DIM * H_DIM * 2);
    unsigned short* wd   = (unsigned short*)alloc((size_t)H_DIM * I_DIM * 2);
    unsigned short* gbuf = (unsigned short*)alloc((size_t)M_TOK * I_DIM * 2);
    unsigned short* AgBf = (unsigned short*)alloc((size_t)H_DIM * 32 * 2);
    unsigned short* AuBf = (unsigned short*)alloc((size_t)H_DIM * 32 * 2);
    unsigned short* AdBf = (unsigned short*)alloc((size_t)I_DIM * 32 * 2);
    unsigned short* BgT  = (unsigned short*)alloc((size_t)I_DIM * 32 * 2);
    unsigned short* BuT  = (unsigned short*)alloc((size_t)I_DIM * 32 * 2);
    unsigned short* BdT  = (unsigned short*)alloc((size_t)H_DIM * 32 * 2);

    (void)hipFuncSetAttribute((const void*)k_gemm256<0>,
        hipFuncAttributeMaxDynamicSharedMemorySize, 131072);
    (void)hipFuncSetAttribute((const void*)k_gemm256<1>,
        hipFuncAttributeMaxDynamicSharedMemorySize, 131072);
    (void)hipFuncSetAttribute((const void*)k_gemm256<2>,
        hipFuncAttributeMaxDynamicSharedMemorySize, 131072);

    // small conversions
    k_conv_f32_bf16<<<128, 256, 0, stream>>>(gate_A, AgBf, (H_DIM * 32) / 4);
    k_conv_f32_bf16<<<128, 256, 0, stream>>>(up_A,   AuBf, (H_DIM * 32) / 4);
    k_conv_f32_bf16<<<344, 256, 0, stream>>>(down_A, AdBf, (I_DIM * 32) / 4);
    k_transposeB<<<(I_DIM * 32 + 255) / 256, 256, 0, stream>>>(gate_B, BgT, I_DIM);
    k_transposeB<<<(I_DIM * 32 + 255) / 256, 256, 0, stream>>>(up_B,   BuT, I_DIM);
    k_transposeB<<<(H_DIM * 32 + 255) / 256, 256, 0, stream>>>(down_B, BdT, H_DIM);
    k_conv_f32_bf16<<<2048, 256, 0, stream>>>(x, xbf, (M_TOK * H_DIM) / 4);

    // W_eff = dequant + 0.02*(A@B)^T   (bf16)
    k_wprep<<<dim3(H_DIM / 128, I_DIM / 128), 256, 0, stream>>>(BgT, AgBf, gate_q, gate_scale, wg, I_DIM, H_DIM);
    k_wprep<<<dim3(H_DIM / 128, I_DIM / 128), 256, 0, stream>>>(BuT, AuBf, up_q,   up_scale,   wu, I_DIM, H_DIM);
    k_wprep<<<dim3(I_DIM / 128, H_DIM / 128), 256, 0, stream>>>(BdT, AdBf, down_q, down_scale, wd, H_DIM, I_DIM);

    // g = x @ Wg^T          (bf16 out)
    k_gemm256<0><<<dim3(I_DIM / 256, M_TOK / 256), 512, 131072, stream>>>(xbf, wg, gbuf, nullptr, M_TOK, I_DIM, H_DIM);
    // h = silu(g) * (x @ Wu^T)   (in-place over g)
    k_gemm256<1><<<dim3(I_DIM / 256, M_TOK / 256), 512, 131072, stream>>>(xbf, wu, gbuf, gbuf, M_TOK, I_DIM, H_DIM);
    // out = h @ Wd^T        (f32)
    k_gemm256<2><<<dim3(H_DIM / 256, M_TOK / 256), 512, 131072, stream>>>(gbuf, wd, d_out, nullptr, M_TOK, H_DIM, I_DIM);
}

// Round 4
// 1227.306 us; speedup vs baseline: 1.6675x; 1.0094x over previous
//
#include <hip/hip_runtime.h>
#include <hip/hip_bf16.h>
#include <stdint.h>

// Problem constants
#define H_DIM 4096
#define I_DIM 11008
#define M_TOK 4096   // B*S = 2*2048

typedef __attribute__((ext_vector_type(8))) short short8;  // 8 bf16 (4 VGPRs)
typedef __attribute__((ext_vector_type(4))) float f32x4;   // 4 fp32

static __device__ __forceinline__ float bf2f(unsigned short u) {
    union { uint32_t i; float f; } v; v.i = ((uint32_t)u) << 16; return v.f;
}
static __device__ __forceinline__ unsigned short f2bf(float f) {
    union { float f; uint32_t i; } v; v.f = f;
    uint32_t r = v.i + 0x7FFF + ((v.i >> 16) & 1);   // RNE
    return (unsigned short)(r >> 16);
}

// async global->LDS, 16B per lane; LDS dest is the wave-uniform base.
static __device__ __forceinline__ void gload16(const void* g, void* l) {
    __builtin_amdgcn_global_load_lds(
        (const __attribute__((address_space(1))) void*)g,
        (__attribute__((address_space(3))) void*)l, 16, 0, 0);
}

// ---------------- small conversion kernels ----------------

__global__ void k_conv_f32_bf16(const float* __restrict__ in,
                                unsigned short* __restrict__ out, int n4) {
    int stride = gridDim.x * blockDim.x;
    for (int i = blockIdx.x * blockDim.x + threadIdx.x; i < n4; i += stride) {
        f32x4 v = ((const f32x4*)in)[i];
        uint64_t p = (uint64_t)f2bf(v[0]) | ((uint64_t)f2bf(v[1]) << 16) |
                     ((uint64_t)f2bf(v[2]) << 32) | ((uint64_t)f2bf(v[3]) << 48);
        ((uint64_t*)out)[i] = p;
    }
}

// B [32][N] f32 -> BT [N][32] bf16
__global__ void k_transposeB(const float* __restrict__ in,
                             unsigned short* __restrict__ out, int N) {
    int idx = blockIdx.x * blockDim.x + threadIdx.x;
    if (idx < N * 32) {
        int n = idx >> 5, r = idx & 31;
        out[idx] = f2bf(in[r * N + n]);
    }
}

// ---------------- W_eff prep: dequant + rank-32 LR via one MFMA step ----------------
__global__ __launch_bounds__(256) void k_wprep(
    const unsigned short* __restrict__ BT,   // [Nw][32] bf16
    const unsigned short* __restrict__ Abf,  // [Kw][32] bf16
    const int* __restrict__ q,               // [Nw][Kw] int32
    const float* __restrict__ scale,         // [Nw]
    unsigned short* __restrict__ W,          // [Nw][Kw] bf16 out
    int Nw, int Kw)
{
    __shared__ unsigned short As[128 * 32];
    __shared__ unsigned short Bs[128 * 32];
    const int tid = threadIdx.x, wid = tid >> 6, lane = tid & 63;
    const int wr = wid >> 1, wc = wid & 1;
    const int brow = blockIdx.y * 128;   // n
    const int bcol = blockIdx.x * 128;   // k
    const int srow = wid * 16 + (lane >> 2), scol = (lane & 3) * 8;

    gload16(BT + (size_t)(brow + srow) * 32 + scol,        &As[wid * 512]);
    gload16(BT + (size_t)(brow + 64 + srow) * 32 + scol,   &As[wid * 512 + 2048]);
    gload16(Abf + (size_t)(bcol + srow) * 32 + scol,       &Bs[wid * 512]);
    gload16(Abf + (size_t)(bcol + 64 + srow) * 32 + scol,  &Bs[wid * 512 + 2048]);
    __syncthreads();

    const int fr = lane & 15, kg = (lane >> 4) * 8;
    f32x4 acc[4][4] = {};
    short8 af[4], bfr[4];
#pragma unroll
    for (int i = 0; i < 4; i++)
        af[i] = *(const short8*)&As[(wr * 64 + i * 16 + fr) * 32 + kg];
#pragma unroll
    for (int j = 0; j < 4; j++)
        bfr[j] = *(const short8*)&Bs[(wc * 64 + j * 16 + fr) * 32 + kg];
#pragma unroll
    for (int i = 0; i < 4; i++)
#pragma unroll
        for (int j = 0; j < 4; j++)
            acc[i][j] = __builtin_amdgcn_mfma_f32_16x16x32_bf16(af[i], bfr[j], acc[i][j], 0, 0, 0);

    const int q4 = lane >> 4;
#pragma unroll
    for (int i = 0; i < 4; i++) {
#pragma unroll
        for (int t = 0; t < 4; t++) {
            int n = brow + wr * 64 + i * 16 + q4 * 4 + t;
            float sc = scale[n] * 0.005f;
#pragma unroll
            for (int j = 0; j < 4; j++) {
                int k = bcol + wc * 64 + j * 16 + fr;
                size_t off = (size_t)n * Kw + k;
                float w = ((float)q[off] - 7.5f) * sc + 0.02f * acc[i][j][t];
                W[off] = f2bf(w);
            }
        }
    }
}

// ---------------- main bf16 GEMM: 256x256, BK=64, deep 4-phase pipeline -----------
// C[M][N] = A[M][K] @ B[N][K]^T ; EPI: 0 bf16, 1 h=silu(g)*acc bf16, 2 f32
// 512 threads = 8 waves (2M x 4N); per-wave C 128x64.
// Whole-tile publish: buf[t&1] fully certified at tile t-1's P3 (vmcnt+barrier).
// Stage stream (half = 2 gloads) runs 3 halves past the dbuf boundary:
//   P0(t): A1(t+1)->buf[t^1]; P1(t): A0(t+2)->buf[t]; P2(t): B0(t+2); P3(t): B1(t+2)
// Each STG's region was last read >=1 trailing-barrier earlier. vmcnt(6) only at
// P3 (waited loads are 4-7 phases old => landed). ds_reads issued at phase top,
// BEFORE the leading barrier -> latency hides under barrier wait.
// Quadrant order (0,0),(0,1),(1,1),(1,0): af reloaded once (A0->A1), bf kept.
template <int EPI>
__global__ __launch_bounds__(512, 1) void k_gemm256(
    const unsigned short* __restrict__ A,   // [M][K] bf16
    const unsigned short* __restrict__ B,   // [N][K] bf16
    void* __restrict__ C,
    const unsigned short* __restrict__ Gin, // EPI==1: g buffer
    int M, int N, int K)
{
    extern __shared__ unsigned short smem[];   // 65536 elems = 128 KiB
    const int tid = threadIdx.x, wid = tid >> 6, lane = tid & 63;
    const int wr = wid >> 2, wc = wid & 3;

    // T1: bijective XCD swizzle
    const int gx = N >> 8;
    const int nwg = gx * (M >> 8);
    int orig = blockIdx.y * gx + blockIdx.x;
    int q8 = nwg >> 3, r8 = nwg & 7;
    int xcd = orig & 7, lid = orig >> 3;
    int wg = (xcd < r8 ? xcd * (q8 + 1) : r8 * (q8 + 1) + (xcd - r8) * q8) + lid;
    const int bcol = (wg % gx) << 8;
    const int brow = (wg / gx) << 8;

    // staging: quarter c covers rows [c*64 + wid*8, +8); lane l -> row l>>3,
    // LDS slot l&7, pre-swizzled global source slot (l&7)^(l>>3)
    const int rg = lane >> 3;
    const int ss = ((lane & 7) ^ rg) * 8;
    const unsigned short* aS[4];
    const unsigned short* bS[4];
#pragma unroll
    for (int c = 0; c < 4; c++) {
        int row = c * 64 + wid * 8 + rg;
        aS[c] = A + (size_t)(brow + row) * K + ss;
        bS[c] = B + (size_t)(bcol + row) * K + ss;
    }
    const int ldw = wid * 512;   // wave chunk within a 64-row quarter (elems)

    f32x4 acc[8][4] = {};
    short8 af[4][2];       // A-frags for current ih (i4 x kk)
    short8 bf[2][2][2];    // B-frags, both jh kept whole K-tile (jh x j2 x kk)
    const int fr = lane & 15, qk = lane >> 4, f7 = fr & 7;
    const int NT = K >> 6;

#define STG(p, k0, doff) gload16((p) + (k0), smem + (doff) + ldw)

    auto DS_A = [&](const unsigned short* Ab, int ih) {
#pragma unroll
        for (int i4 = 0; i4 < 4; ++i4)
#pragma unroll
            for (int kk = 0; kk < 2; ++kk)
                af[i4][kk] = *(const short8*)&Ab[
                    (ih * 128 + wr * 64 + i4 * 16 + fr) * 64 +
                    ((((kk << 2) | qk) ^ f7) << 3)];
    };
    auto DS_B = [&](const unsigned short* Bb, int jh) {
#pragma unroll
        for (int j2 = 0; j2 < 2; ++j2)
#pragma unroll
            for (int kk = 0; kk < 2; ++kk)
                bf[jh][j2][kk] = *(const short8*)&Bb[
                    (jh * 128 + wc * 32 + j2 * 16 + fr) * 64 +
                    ((((kk << 2) | qk) ^ f7) << 3)];
    };
    auto MFMAQ = [&](int ih, int jh) {
        __builtin_amdgcn_s_setprio(1);
#pragma unroll
        for (int i4 = 0; i4 < 4; ++i4)
#pragma unroll
            for (int j2 = 0; j2 < 2; ++j2)
#pragma unroll
                for (int kk = 0; kk < 2; ++kk)
                    acc[ih * 4 + i4][jh * 2 + j2] =
                        __builtin_amdgcn_mfma_f32_16x16x32_bf16(
                            af[i4][kk], bf[jh][j2][kk],
                            acc[ih * 4 + i4][jh * 2 + j2], 0, 0, 0);
        __builtin_amdgcn_s_setprio(0);
    };

    // prologue: stage stream halves s0..s6 (tile0: A0,B0,B1,A1; tile1: A0,B0,B1)
    STG(aS[0], 0, 0);      STG(aS[1], 0, 4096);
    STG(bS[0], 0, 16384);  STG(bS[1], 0, 20480);
    STG(bS[2], 0, 24576);  STG(bS[3], 0, 28672);
    STG(aS[2], 0, 8192);   STG(aS[3], 0, 12288);
    if (NT > 1) {
        STG(aS[0], 64, 32768);          STG(aS[1], 64, 32768 + 4096);
        STG(bS[0], 64, 32768 + 16384);  STG(bS[1], 64, 32768 + 20480);
        STG(bS[2], 64, 32768 + 24576);  STG(bS[3], 64, 32768 + 28672);
    }
    asm volatile("s_waitcnt vmcnt(6)" ::: "memory");   // tile 0 landed
    __builtin_amdgcn_s_barrier();

    auto TILE = [&](int t, bool s1, bool s2) {
        const int bsel = (t & 1) * 32768, osel = 32768 - bsel;
        const unsigned short* Ab = smem + bsel;
        const unsigned short* Bb = Ab + 16384;
        const int kA = (t + 1) << 6, kB = (t + 2) << 6;
        // P0: reads A0,B0; stages A1(t+1) -> other buffer
        DS_A(Ab, 0); DS_B(Bb, 0);
        if (s1) { STG(aS[2], kA, osel + 8192); STG(aS[3], kA, osel + 12288); }
        __builtin_amdgcn_s_barrier();
        asm volatile("s_waitcnt lgkmcnt(0)" ::: "memory");
        MFMAQ(0, 0);
        __builtin_amdgcn_s_barrier();
        // P1: reads B1; stages A0(t+2) -> this buffer (A0 reads done at P0 fence)
        DS_B(Bb, 1);
        if (s2) { STG(aS[0], kB, bsel); STG(aS[1], kB, bsel + 4096); }
        __builtin_amdgcn_s_barrier();
        asm volatile("s_waitcnt lgkmcnt(0)" ::: "memory");
        MFMAQ(0, 1);
        __builtin_amdgcn_s_barrier();
        // P2: reads A1; stages B0(t+2) (B0 reads done at P0 fence)
        DS_A(Ab, 1);
        if (s2) { STG(bS[0], kB, bsel + 16384); STG(bS[1], kB, bsel + 20480); }
        __builtin_amdgcn_s_barrier();
        asm volatile("s_waitcnt lgkmcnt(0)" ::: "memory");
        MFMAQ(1, 1);
        __builtin_amdgcn_s_barrier();
        // P3: all-reg; stages B1(t+2) (B1 reads done at P1 fence); cert tile t+1
        if (s2) {
            STG(bS[2], kB, bsel + 24576); STG(bS[3], kB, bsel + 28672);
            asm volatile("s_waitcnt vmcnt(6)" ::: "memory");
        } else if (s1) {
            asm volatile("s_waitcnt vmcnt(0)" ::: "memory");
        }
        __builtin_amdgcn_s_barrier();
        MFMAQ(1, 0);
        __builtin_amdgcn_s_barrier();
    };

    int t = 0;
    for (; t < NT - 2; ++t) TILE(t, true, true);
    if (t == NT - 2) { TILE(t, true, false); ++t; }
    TILE(t, false, false);
#undef STG

    // epilogue
    const int q4 = lane >> 4;
#pragma unroll
    for (int i = 0; i < 8; ++i) {
#pragma unroll
        for (int j = 0; j < 4; ++j) {
#pragma unroll
            for (int tt = 0; tt < 4; ++tt) {
                int m = brow + (i >> 2) * 128 + wr * 64 + (i & 3) * 16 + q4 * 4 + tt;
                int n = bcol + (j >> 1) * 128 + wc * 32 + (j & 1) * 16 + fr;
                size_t off = (size_t)m * N + n;
                float v = acc[i][j][tt];
                if (EPI == 0) {
                    ((unsigned short*)C)[off] = f2bf(v);
                } else if (EPI == 1) {
                    float g = bf2f(Gin[off]);
                    float s = g / (1.0f + __expf(-g));   // silu(g)
                    ((unsigned short*)C)[off] = f2bf(s * v);
                } else {
                    ((float*)C)[off] = v;
                }
            }
        }
    }
}

// ---------------- host launch ----------------
extern "C" void kernel_launch(void* const* d_in, const int* in_sizes, int n_in,
                              void* d_out, int out_size, void* d_ws, size_t ws_size,
                              hipStream_t stream) {
    (void)in_sizes; (void)n_in; (void)out_size; (void)ws_size;
    const float* x          = (const float*)d_in[0];
    const int*   gate_q     = (const int*)d_in[1];
    const float* gate_scale = (const float*)d_in[2];
    const float* gate_A     = (const float*)d_in[3];
    const float* gate_B     = (const float*)d_in[4];
    const int*   up_q       = (const int*)d_in[5];
    const float* up_scale   = (const float*)d_in[6];
    const float* up_A       = (const float*)d_in[7];
    const float* up_B       = (const float*)d_in[8];
    const int*   down_q     = (const int*)d_in[9];
    const float* down_scale = (const float*)d_in[10];
    const float* down_A     = (const float*)d_in[11];
    const float* down_B     = (const float*)d_in[12];

    char* ws = (char*)d_ws;
    size_t off = 0;
    auto alloc = [&](size_t bytes) {
        void* p = ws + off; off += (bytes + 255) & ~(size_t)255; return p;
    };
    unsigned short* xbf  = (unsigned short*)alloc((size_t)M_TOK * H_DIM * 2);
    unsigned short* wg   = (unsigned short*)alloc((size_t)I_DIM * H_DIM * 2);
    unsigned short* wu   = (unsigned short*)alloc((size_t)I_DIM * H_DIM * 2);
    unsigned short* wd   = (unsigned short*)alloc((size_t)H_DIM * I_DIM * 2);
    unsigned short* gbuf = (unsigned short*)alloc((size_t)M_TOK * I_DIM * 2);
    unsigned short* AgBf = (unsigned short*)alloc((size_t)H_DIM * 32 * 2);
    unsigned short* AuBf = (unsigned short*)alloc((size_t)H_DIM * 32 * 2);
    unsigned short* AdBf = (unsigned short*)alloc((size_t)I_DIM * 32 * 2);
    unsigned short* BgT  = (unsigned short*)alloc((size_t)I_DIM * 32 * 2);
    unsigned short* BuT  = (unsigned short*)alloc((size_t)I_DIM * 32 * 2);
    unsigned short* BdT  = (unsigned short*)alloc((size_t)H_DIM * 32 * 2);

    (void)hipFuncSetAttribute((const void*)k_gemm256<0>,
        hipFuncAttributeMaxDynamicSharedMemorySize, 131072);
    (void)hipFuncSetAttribute((const void*)k_gemm256<1>,
        hipFuncAttributeMaxDynamicSharedMemorySize, 131072);
    (void)hipFuncSetAttribute((const void*)k_gemm256<2>,
        hipFuncAttributeMaxDynamicSharedMemorySize, 131072);

    // small conversions
    k_conv_f32_bf16<<<128, 256, 0, stream>>>(gate_A, AgBf, (H_DIM * 32) / 4);
    k_conv_f32_bf16<<<128, 256, 0, stream>>>(up_A,   AuBf, (H_DIM * 32) / 4);
    k_conv_f32_bf16<<<344, 256, 0, stream>>>(down_A, AdBf, (I_DIM * 32) / 4);
    k_transposeB<<<(I_DIM * 32 + 255) / 256, 256, 0, stream>>>(gate_B, BgT, I_DIM);
    k_transposeB<<<(I_DIM * 32 + 255) / 256, 256, 0, stream>>>(up_B,   BuT, I_DIM);
    k_transposeB<<<(H_DIM * 32 + 255) / 256, 256, 0, stream>>>(down_B, BdT, H_DIM);
    k_conv_f32_bf16<<<2048, 256, 0, stream>>>(x, xbf, (M_TOK * H_DIM) / 4);

    // W_eff = dequant + 0.02*(A@B)^T   (bf16)
    k_wprep<<<dim3(H_DIM / 128, I_DIM / 128), 256, 0, stream>>>(BgT, AgBf, gate_q, gate_scale, wg, I_DIM, H_DIM);
    k_wprep<<<dim3(H_DIM / 128, I_DIM / 128), 256, 0, stream>>>(BuT, AuBf, up_q,   up_scale,   wu, I_DIM, H_DIM);
    k_wprep<<<dim3(I_DIM / 128, H_DIM / 128), 256, 0, stream>>>(BdT, AdBf, down_q, down_scale, wd, H_DIM, I_DIM);

    // g = x @ Wg^T          (bf16 out)
    k_gemm256<0><<<dim3(I_DIM / 256, M_TOK / 256), 512, 131072, stream>>>(xbf, wg, gbuf, nullptr, M_TOK, I_DIM, H_DIM);
    // h = silu(g) * (x @ Wu^T)   (in-place over g)
    k_gemm256<1><<<dim3(I_DIM / 256, M_TOK / 256), 512, 131072, stream>>>(xbf, wu, gbuf, gbuf, M_TOK, I_DIM, H_DIM);
    // out = h @ Wd^T        (f32)
    k_gemm256<2><<<dim3(H_DIM / 256, M_TOK / 256), 512, 131072, stream>>>(gbuf, wd, d_out, nullptr, M_TOK, H_DIM, I_DIM);
}

// Round 5
// 1170.122 us; speedup vs baseline: 1.7490x; 1.0489x over previous
//
#include <hip/hip_runtime.h>
#include <hip/hip_bf16.h>
#include <stdint.h>

// Problem constants
#define H_DIM 4096
#define I_DIM 11008
#define M_TOK 4096   // B*S = 2*2048

typedef __attribute__((ext_vector_type(8))) short short8;  // 8 bf16 (4 VGPRs)
typedef __attribute__((ext_vector_type(4))) float f32x4;   // 4 fp32

static __device__ __forceinline__ float bf2f(unsigned short u) {
    union { uint32_t i; float f; } v; v.i = ((uint32_t)u) << 16; return v.f;
}
static __device__ __forceinline__ unsigned short f2bf(float f) {
    union { float f; uint32_t i; } v; v.f = f;
    uint32_t r = v.i + 0x7FFF + ((v.i >> 16) & 1);   // RNE
    return (unsigned short)(r >> 16);
}

// async global->LDS, 16B per lane; LDS dest is the wave-uniform base.
static __device__ __forceinline__ void gload16(const void* g, void* l) {
    __builtin_amdgcn_global_load_lds(
        (const __attribute__((address_space(1))) void*)g,
        (__attribute__((address_space(3))) void*)l, 16, 0, 0);
}

// ---------------- small conversion kernels ----------------

__global__ void k_conv_f32_bf16(const float* __restrict__ in,
                                unsigned short* __restrict__ out, int n4) {
    int stride = gridDim.x * blockDim.x;
    for (int i = blockIdx.x * blockDim.x + threadIdx.x; i < n4; i += stride) {
        f32x4 v = ((const f32x4*)in)[i];
        uint64_t p = (uint64_t)f2bf(v[0]) | ((uint64_t)f2bf(v[1]) << 16) |
                     ((uint64_t)f2bf(v[2]) << 32) | ((uint64_t)f2bf(v[3]) << 48);
        ((uint64_t*)out)[i] = p;
    }
}

// B [32][N] f32 -> BT [N][32] bf16
__global__ void k_transposeB(const float* __restrict__ in,
                             unsigned short* __restrict__ out, int N) {
    int idx = blockIdx.x * blockDim.x + threadIdx.x;
    if (idx < N * 32) {
        int n = idx >> 5, r = idx & 31;
        out[idx] = f2bf(in[r * N + n]);
    }
}

// ---------------- W_eff prep: dequant + rank-32 LR via one MFMA step ----------------
__global__ __launch_bounds__(256) void k_wprep(
    const unsigned short* __restrict__ BT,   // [Nw][32] bf16
    const unsigned short* __restrict__ Abf,  // [Kw][32] bf16
    const int* __restrict__ q,               // [Nw][Kw] int32
    const float* __restrict__ scale,         // [Nw]
    unsigned short* __restrict__ W,          // [Nw][Kw] bf16 out
    int Nw, int Kw)
{
    __shared__ unsigned short As[128 * 32];
    __shared__ unsigned short Bs[128 * 32];
    const int tid = threadIdx.x, wid = tid >> 6, lane = tid & 63;
    const int wr = wid >> 1, wc = wid & 1;
    const int brow = blockIdx.y * 128;   // n
    const int bcol = blockIdx.x * 128;   // k
    const int srow = wid * 16 + (lane >> 2), scol = (lane & 3) * 8;

    gload16(BT + (size_t)(brow + srow) * 32 + scol,        &As[wid * 512]);
    gload16(BT + (size_t)(brow + 64 + srow) * 32 + scol,   &As[wid * 512 + 2048]);
    gload16(Abf + (size_t)(bcol + srow) * 32 + scol,       &Bs[wid * 512]);
    gload16(Abf + (size_t)(bcol + 64 + srow) * 32 + scol,  &Bs[wid * 512 + 2048]);
    __syncthreads();

    const int fr = lane & 15, kg = (lane >> 4) * 8;
    f32x4 acc[4][4] = {};
    short8 af[4], bfr[4];
#pragma unroll
    for (int i = 0; i < 4; i++)
        af[i] = *(const short8*)&As[(wr * 64 + i * 16 + fr) * 32 + kg];
#pragma unroll
    for (int j = 0; j < 4; j++)
        bfr[j] = *(const short8*)&Bs[(wc * 64 + j * 16 + fr) * 32 + kg];
#pragma unroll
    for (int i = 0; i < 4; i++)
#pragma unroll
        for (int j = 0; j < 4; j++)
            acc[i][j] = __builtin_amdgcn_mfma_f32_16x16x32_bf16(af[i], bfr[j], acc[i][j], 0, 0, 0);

    const int q4 = lane >> 4;
#pragma unroll
    for (int i = 0; i < 4; i++) {
#pragma unroll
        for (int t = 0; t < 4; t++) {
            int n = brow + wr * 64 + i * 16 + q4 * 4 + t;
            float sc = scale[n] * 0.005f;
#pragma unroll
            for (int j = 0; j < 4; j++) {
                int k = bcol + wc * 64 + j * 16 + fr;
                size_t off = (size_t)n * Kw + k;
                float w = ((float)q[off] - 7.5f) * sc + 0.02f * acc[i][j][t];
                W[off] = f2bf(w);
            }
        }
    }
}

// ---------------- main bf16 GEMM: 256x256, BK=64, read-pipelined 8-phase ----------
// C[M][N] = A[M][K] @ B[N][K]^T ; EPI: 0 bf16, 1 h=silu(g)*acc bf16, 2 f32
// 512 threads = 8 waves (2M x 4N); per-wave C 128x64.
// Each K-tile = 8 phases of 8 MFMA (quadrant x kk). Phase p issues the ds_reads
// for phase p+1 BEFORE its barrier, so LDS service overlaps phase p's MFMA and
// the barrier wait (kills the same-phase read->consume herd). Frag regs rotate:
// afX/afY (A slices, 2-phase lifetime), bfX/bfY (B slices; B0 re-read at P5/P6).
// Staging: one half-tile (2 gload_lds) after the barrier of P0(B0,t+1),
// P2(A0,t+2), P4(B1,t+2), P6(A1,t+2). One counted vmcnt(2) per tile at P4
// (pre-barrier) certifies everything except the newest stage (A0,t+2) --
// covering all reads through the next tile's P4. Barriers: 8/tile.
template <int EPI>
__global__ __launch_bounds__(512, 1) void k_gemm256(
    const unsigned short* __restrict__ A,   // [M][K] bf16
    const unsigned short* __restrict__ B,   // [N][K] bf16
    void* __restrict__ C,
    const unsigned short* __restrict__ Gin, // EPI==1: g buffer
    int M, int N, int K)
{
    extern __shared__ unsigned short smem[];   // 65536 elems = 128 KiB
    const int tid = threadIdx.x, wid = tid >> 6, lane = tid & 63;
    const int wr = wid >> 2, wc = wid & 3;

    // T1: bijective XCD swizzle
    const int gx = N >> 8;
    const int nwg = gx * (M >> 8);
    int orig = blockIdx.y * gx + blockIdx.x;
    int q8 = nwg >> 3, r8 = nwg & 7;
    int xcd = orig & 7, lid = orig >> 3;
    int wg = (xcd < r8 ? xcd * (q8 + 1) : r8 * (q8 + 1) + (xcd - r8) * q8) + lid;
    const int bcol = (wg % gx) << 8;
    const int brow = (wg / gx) << 8;

    // staging: quarter c covers rows [c*64 + wid*8, +8); lane l -> row l>>3,
    // LDS slot l&7, pre-swizzled global source slot (l&7)^(l>>3)
    const int rg = lane >> 3;
    const int ss = ((lane & 7) ^ rg) * 8;
    const unsigned short* aS[4];
    const unsigned short* bS[4];
#pragma unroll
    for (int c = 0; c < 4; c++) {
        int row = c * 64 + wid * 8 + rg;
        aS[c] = A + (size_t)(brow + row) * K + ss;
        bS[c] = B + (size_t)(bcol + row) * K + ss;
    }
    const int ldw = wid * 512;   // wave chunk within a 64-row quarter (elems)

    f32x4 acc[8][4] = {};
    short8 afX[4], afY[4];   // A frag slices (4 x b128 each)
    short8 bfX[2], bfY[2];   // B frag slices (2 x b128 each)
    const int fr = lane & 15, qk = lane >> 4, f7 = fr & 7;
    const int NT = K >> 6;

    // per-(buffer, kk) read base pointers; all later offsets are constants.
    const unsigned short* aP[2][2];
    const unsigned short* bP[2][2];
#pragma unroll
    for (int b = 0; b < 2; ++b)
#pragma unroll
        for (int kk = 0; kk < 2; ++kk) {
            int swz = (((kk << 2) | qk) ^ f7) << 3;
            aP[b][kk] = smem + b * 32768 + (wr * 64 + fr) * 64 + swz;
            bP[b][kk] = smem + b * 32768 + 16384 + (wc * 32 + fr) * 64 + swz;
        }

#define STG(p, k0, doff) gload16((p) + (k0), smem + (doff) + ldw)
#define LDA8(dst, P, IH) { _Pragma("unroll") \
    for (int i4 = 0; i4 < 4; ++i4) dst[i4] = *(const short8*)&(P)[(IH)*8192 + i4*1024]; }
#define LDB4(dst, P, JH) { _Pragma("unroll") \
    for (int j2 = 0; j2 < 2; ++j2) dst[j2] = *(const short8*)&(P)[(JH)*8192 + j2*1024]; }
#define MF8(AF, BF, IH, JH) { __builtin_amdgcn_s_setprio(1); \
    _Pragma("unroll") for (int i4 = 0; i4 < 4; ++i4) \
    _Pragma("unroll") for (int j2 = 0; j2 < 2; ++j2) \
        acc[(IH)*4+i4][(JH)*2+j2] = __builtin_amdgcn_mfma_f32_16x16x32_bf16( \
            AF[i4], BF[j2], acc[(IH)*4+i4][(JH)*2+j2], 0, 0, 0); \
    __builtin_amdgcn_s_setprio(0); }

// One K-tile. BB: compile-time buffer (0/1). S2: stage t+2 trio. SB0: stage
// B0(t+1). CERT: 0 none / 1 vmcnt(2) / 2 vmcnt(0). RNEXT: issue next-tile reads.
#define TILE(BB, t, S2, SB0, CERT, RNEXT) { \
    const int kN = ((t) + 1) << 6, kN2 = ((t) + 2) << 6; \
    /* P0: reads(P1): A0k1->afY, B0k1->bfY */ \
    LDA8(afY, aP[BB][1], 0); LDB4(bfY, bP[BB][1], 0); \
    __builtin_amdgcn_s_barrier(); \
    if (SB0) { STG(bS[0], kN, (1-(BB))*32768 + 16384); \
               STG(bS[1], kN, (1-(BB))*32768 + 20480); } \
    MF8(afX, bfX, 0, 0); \
    /* P1: reads(P2): B1k0->bfX */ \
    LDB4(bfX, bP[BB][0], 1); \
    __builtin_amdgcn_s_barrier(); \
    MF8(afY, bfY, 0, 0); \
    /* P2: reads(P3): B1k1->bfY */ \
    LDB4(bfY, bP[BB][1], 1); \
    __builtin_amdgcn_s_barrier(); \
    if (S2) { STG(aS[0], kN2, (BB)*32768); STG(aS[1], kN2, (BB)*32768 + 4096); } \
    MF8(afX, bfX, 0, 1); \
    /* P3: reads(P4): A1k0->afX */ \
    LDA8(afX, aP[BB][0], 1); \
    __builtin_amdgcn_s_barrier(); \
    MF8(afY, bfY, 0, 1); \
    /* P4: reads(P5): A1k1->afY ; tile-publish cert (pre-barrier) */ \
    LDA8(afY, aP[BB][1], 1); \
    if (CERT == 1) asm volatile("s_waitcnt vmcnt(2)" ::: "memory"); \
    if (CERT == 2) asm volatile("s_waitcnt vmcnt(0)" ::: "memory"); \
    __builtin_amdgcn_s_barrier(); \
    if (S2) { STG(bS[2], kN2, (BB)*32768 + 24576); STG(bS[3], kN2, (BB)*32768 + 28672); } \
    MF8(afX, bfX, 1, 1); \
    /* P5: reads(P6): B0k0->bfX (re-read) */ \
    LDB4(bfX, bP[BB][0], 0); \
    __builtin_amdgcn_s_barrier(); \
    MF8(afY, bfY, 1, 1); \
    /* P6: reads(P7): B0k1->bfY */ \
    LDB4(bfY, bP[BB][1], 0); \
    __builtin_amdgcn_s_barrier(); \
    if (S2) { STG(aS[2], kN2, (BB)*32768 + 8192); STG(aS[3], kN2, (BB)*32768 + 12288); } \
    MF8(afX, bfX, 1, 0); \
    /* P7: reads(P0,t+1): A0k0->afX, B0k0->bfX from other buffer */ \
    if (RNEXT) { LDA8(afX, aP[1-(BB)][0], 0); LDB4(bfX, bP[1-(BB)][0], 0); } \
    __builtin_amdgcn_s_barrier(); \
    MF8(afY, bfY, 1, 0); \
}

    // prologue: tile0 full (A0,B0,B1,A1 = 8 loads) + tile1 A0,B1,A1 (6 loads).
    // B0(1) is staged in-loop at P0(0).
    STG(aS[0], 0, 0);      STG(aS[1], 0, 4096);
    STG(bS[0], 0, 16384);  STG(bS[1], 0, 20480);
    STG(bS[2], 0, 24576);  STG(bS[3], 0, 28672);
    STG(aS[2], 0, 8192);   STG(aS[3], 0, 12288);
    STG(aS[0], 64, 32768);         STG(aS[1], 64, 32768 + 4096);
    STG(bS[2], 64, 32768 + 24576); STG(bS[3], 64, 32768 + 28672);
    STG(aS[2], 64, 32768 + 8192);  STG(aS[3], 64, 32768 + 12288);
    asm volatile("s_waitcnt vmcnt(6)" ::: "memory");   // tile 0 landed
    __builtin_amdgcn_s_barrier();
    LDA8(afX, aP[0][0], 0); LDB4(bfX, bP[0][0], 0);    // reads for P0(0)

    int t = 0;
    for (; t + 4 <= NT; t += 2) {
        TILE(0, t,     1, 1, 1, 1);
        TILE(1, t + 1, 1, 1, 1, 1);
    }
    TILE(0, NT - 2, 0, 1, 2, 1);
    TILE(1, NT - 1, 0, 0, 0, 0);

#undef TILE
#undef MF8
#undef LDB4
#undef LDA8
#undef STG

    // epilogue
    const int q4 = lane >> 4;
#pragma unroll
    for (int i = 0; i < 8; ++i) {
#pragma unroll
        for (int j = 0; j < 4; ++j) {
#pragma unroll
            for (int tt = 0; tt < 4; ++tt) {
                int m = brow + (i >> 2) * 128 + wr * 64 + (i & 3) * 16 + q4 * 4 + tt;
                int n = bcol + (j >> 1) * 128 + wc * 32 + (j & 1) * 16 + fr;
                size_t off = (size_t)m * N + n;
                float v = acc[i][j][tt];
                if (EPI == 0) {
                    ((unsigned short*)C)[off] = f2bf(v);
                } else if (EPI == 1) {
                    float g = bf2f(Gin[off]);
                    float s = g / (1.0f + __expf(-g));   // silu(g)
                    ((unsigned short*)C)[off] = f2bf(s * v);
                } else {
                    ((float*)C)[off] = v;
                }
            }
        }
    }
}

// ---------------- host launch ----------------
extern "C" void kernel_launch(void* const* d_in, const int* in_sizes, int n_in,
                              void* d_out, int out_size, void* d_ws, size_t ws_size,
                              hipStream_t stream) {
    (void)in_sizes; (void)n_in; (void)out_size; (void)ws_size;
    const float* x          = (const float*)d_in[0];
    const int*   gate_q     = (const int*)d_in[1];
    const float* gate_scale = (const float*)d_in[2];
    const float* gate_A     = (const float*)d_in[3];
    const float* gate_B     = (const float*)d_in[4];
    const int*   up_q       = (const int*)d_in[5];
    const float* up_scale   = (const float*)d_in[6];
    const float* up_A       = (const float*)d_in[7];
    const float* up_B       = (const float*)d_in[8];
    const int*   down_q     = (const int*)d_in[9];
    const float* down_scale = (const float*)d_in[10];
    const float* down_A     = (const float*)d_in[11];
    const float* down_B     = (const float*)d_in[12];

    char* ws = (char*)d_ws;
    size_t off = 0;
    auto alloc = [&](size_t bytes) {
        void* p = ws + off; off += (bytes + 255) & ~(size_t)255; return p;
    };
    unsigned short* xbf  = (unsigned short*)alloc((size_t)M_TOK * H_DIM * 2);
    unsigned short* wg   = (unsigned short*)alloc((size_t)I_DIM * H_DIM * 2);
    unsigned short* wu   = (unsigned short*)alloc((size_t)I_DIM * H_DIM * 2);
    unsigned short* wd   = (unsigned short*)alloc((size_t)H_DIM * I_DIM * 2);
    unsigned short* gbuf = (unsigned short*)alloc((size_t)M_TOK * I_DIM * 2);
    unsigned short* AgBf = (unsigned short*)alloc((size_t)H_DIM * 32 * 2);
    unsigned short* AuBf = (unsigned short*)alloc((size_t)H_DIM * 32 * 2);
    unsigned short* AdBf = (unsigned short*)alloc((size_t)I_DIM * 32 * 2);
    unsigned short* BgT  = (unsigned short*)alloc((size_t)I_DIM * 32 * 2);
    unsigned short* BuT  = (unsigned short*)alloc((size_t)I_DIM * 32 * 2);
    unsigned short* BdT  = (unsigned short*)alloc((size_t)H_DIM * 32 * 2);

    (void)hipFuncSetAttribute((const void*)k_gemm256<0>,
        hipFuncAttributeMaxDynamicSharedMemorySize, 131072);
    (void)hipFuncSetAttribute((const void*)k_gemm256<1>,
        hipFuncAttributeMaxDynamicSharedMemorySize, 131072);
    (void)hipFuncSetAttribute((const void*)k_gemm256<2>,
        hipFuncAttributeMaxDynamicSharedMemorySize, 131072);

    // small conversions
    k_conv_f32_bf16<<<128, 256, 0, stream>>>(gate_A, AgBf, (H_DIM * 32) / 4);
    k_conv_f32_bf16<<<128, 256, 0, stream>>>(up_A,   AuBf, (H_DIM * 32) / 4);
    k_conv_f32_bf16<<<344, 256, 0, stream>>>(down_A, AdBf, (I_DIM * 32) / 4);
    k_transposeB<<<(I_DIM * 32 + 255) / 256, 256, 0, stream>>>(gate_B, BgT, I_DIM);
    k_transposeB<<<(I_DIM * 32 + 255) / 256, 256, 0, stream>>>(up_B,   BuT, I_DIM);
    k_transposeB<<<(H_DIM * 32 + 255) / 256, 256, 0, stream>>>(down_B, BdT, H_DIM);
    k_conv_f32_bf16<<<2048, 256, 0, stream>>>(x, xbf, (M_TOK * H_DIM) / 4);

    // W_eff = dequant + 0.02*(A@B)^T   (bf16)
    k_wprep<<<dim3(H_DIM / 128, I_DIM / 128), 256, 0, stream>>>(BgT, AgBf, gate_q, gate_scale, wg, I_DIM, H_DIM);
    k_wprep<<<dim3(H_DIM / 128, I_DIM / 128), 256, 0, stream>>>(BuT, AuBf, up_q,   up_scale,   wu, I_DIM, H_DIM);
    k_wprep<<<dim3(I_DIM / 128, H_DIM / 128), 256, 0, stream>>>(BdT, AdBf, down_q, down_scale, wd, H_DIM, I_DIM);

    // g = x @ Wg^T          (bf16 out)
    k_gemm256<0><<<dim3(I_DIM / 256, M_TOK / 256), 512, 131072, stream>>>(xbf, wg, gbuf, nullptr, M_TOK, I_DIM, H_DIM);
    // h = silu(g) * (x @ Wu^T)   (in-place over g)
    k_gemm256<1><<<dim3(I_DIM / 256, M_TOK / 256), 512, 131072, stream>>>(xbf, wu, gbuf, gbuf, M_TOK, I_DIM, H_DIM);
    // out = h @ Wd^T        (f32)
    k_gemm256<2><<<dim3(H_DIM / 256, M_TOK / 256), 512, 131072, stream>>>(gbuf, wd, d_out, nullptr, M_TOK, H_DIM, I_DIM);
}